// Round 6
// baseline (1405.362 us; speedup 1.0000x reference)
//
#include <hip/hip_runtime.h>
#include <hip/hip_bf16.h>

#define N_NODES 50000
#define N_EDGES 800000
#define N_GRAPHS 64

// ---------------------------------------------------------------------------
// CSR build (once per call; edge_index is shared by all 3 layers).
// ---------------------------------------------------------------------------
__global__ __launch_bounds__(256) void hist_kernel(const int* __restrict__ ei,
                                                   int* __restrict__ deg, int E) {
  int e = blockIdx.x * 256 + threadIdx.x;
  if (e < E) atomicAdd(&deg[ei[E + e]], 1);
}

__global__ __launch_bounds__(1024) void scan_kernel(const int* __restrict__ deg,
                                                    int* __restrict__ row_start,
                                                    int* __restrict__ cursor, int N) {
  __shared__ int part[1024];
  const int t = threadIdx.x;
  const int C = (N + 1023) / 1024;
  const int b0 = min(t * C, N);
  const int b1 = min(b0 + C, N);
  int s = 0;
  for (int i = b0; i < b1; ++i) s += deg[i];
  part[t] = s;
  __syncthreads();
  for (int off = 1; off < 1024; off <<= 1) {
    int v = (t >= off) ? part[t - off] : 0;
    __syncthreads();
    part[t] += v;
    __syncthreads();
  }
  int ex = (t == 0) ? 0 : part[t - 1];
  for (int i = b0; i < b1; ++i) {
    row_start[i] = ex;
    cursor[i] = ex;
    ex += deg[i];
  }
  if (t == 1023) row_start[N] = part[1023];
}

__global__ __launch_bounds__(256) void scatter_kernel(const int* __restrict__ ei,
                                                      int* __restrict__ cursor,
                                                      int2* __restrict__ epair, int E) {
  int e = blockIdx.x * 256 + threadIdx.x;
  if (e < E) {
    int d = ei[E + e];
    int p = atomicAdd(&cursor[d], 1);
    epair[p] = make_int2(e, ei[e]);  // (edge id, src node)
  }
}

// ---------------------------------------------------------------------------
// Fused GINE gather. ONE WAVE PER NODE (FPL = DIN/64 features per lane).
// Weights in LDS, pair-interleaved so a lane's FPL features are one ds_read.
// 4-edge groups: 32 ds_reads feed 4*FPL*32 FMAs; ea rows via uniform s_loads.
// Group metadata (epair, src x, mask) is software-pipelined one group ahead
// so the FMA block of group i covers the VMEM/SMEM latency of group i+1.
// ---------------------------------------------------------------------------
template <int DIN>
__global__ __launch_bounds__(256) void gine_gather(
    const float* __restrict__ x, const float* __restrict__ ea,
    const int* __restrict__ row_start, const int2* __restrict__ epair,
    const float* __restrict__ lew, const float* __restrict__ leb,
    float* __restrict__ hpre, int N) {
  constexpr int FPL = DIN / 64;
  __shared__ float wlds[32 * DIN];  // [k][lane*FPL+p] = lew[k*DIN + p*64 + lane]
  const int tid = threadIdx.x;
  for (int i = tid; i < 32 * DIN; i += 256) {
    const int k = i / DIN;
    const int c = i - k * DIN;
    const int l = c / FPL;
    const int p = c - l * FPL;
    wlds[i] = lew[k * DIN + p * 64 + l];
  }
  __syncthreads();

  const int n = blockIdx.x * 4 + (tid >> 6);
  if (n >= N) return;
  const int lane = tid & 63;

  float bb[FPL], acc[FPL];
#pragma unroll
  for (int p = 0; p < FPL; ++p) {
    bb[p] = leb[p * 64 + lane];
    acc[p] = 0.f;
  }
  const int e0 = row_start[n];
  const int e1 = row_start[n + 1];

  if (e1 > e0) {
    int ce[4], cs[4];
    float cm[4], cx[4][FPL];
    auto LOADM = [&](int i, int* e_, int* s_, float* m_, float (*x_)[FPL]) {
#pragma unroll
      for (int j = 0; j < 4; ++j) {
        const int idx = (i + j < e1) ? (i + j) : (e1 - 1);
        const int2 pr = epair[idx];  // uniform idx -> s_load
        e_[j] = __builtin_amdgcn_readfirstlane(pr.x);
        s_[j] = __builtin_amdgcn_readfirstlane(pr.y);
        m_[j] = (i + j < e1) ? 1.f : 0.f;
      }
#pragma unroll
      for (int j = 0; j < 4; ++j)
#pragma unroll
        for (int p = 0; p < FPL; ++p)
          x_[j][p] = x[(size_t)s_[j] * DIN + p * 64 + lane];
    };

    LOADM(e0, ce, cs, cm, cx);
    for (int i = e0; i < e1; i += 4) {
      int ne[4], ns_[4];
      float nm[4], nx[4][FPL];
      if (i + 4 < e1) LOADM(i + 4, ne, ns_, nm, nx);  // prefetch next group

      const float* __restrict__ r0 = ea + (size_t)ce[0] * 32;
      const float* __restrict__ r1 = ea + (size_t)ce[1] * 32;
      const float* __restrict__ r2 = ea + (size_t)ce[2] * 32;
      const float* __restrict__ r3 = ea + (size_t)ce[3] * 32;

      float t[4][FPL];
#pragma unroll
      for (int j = 0; j < 4; ++j)
#pragma unroll
        for (int p = 0; p < FPL; ++p) t[j][p] = bb[p];

#pragma unroll
      for (int k = 0; k < 32; ++k) {
        float wk[FPL];
        if constexpr (FPL == 2) {
          const float2 wv = *(const float2*)&wlds[k * DIN + 2 * lane];
          wk[0] = wv.x;
          wk[1] = wv.y;
        } else {
          wk[0] = wlds[k * 64 + lane];
        }
        const float a0 = r0[k], a1 = r1[k], a2 = r2[k], a3 = r3[k];
#pragma unroll
        for (int p = 0; p < FPL; ++p) {
          t[0][p] = fmaf(a0, wk[p], t[0][p]);
          t[1][p] = fmaf(a1, wk[p], t[1][p]);
          t[2][p] = fmaf(a2, wk[p], t[2][p]);
          t[3][p] = fmaf(a3, wk[p], t[3][p]);
        }
      }
#pragma unroll
      for (int j = 0; j < 4; ++j)
#pragma unroll
        for (int p = 0; p < FPL; ++p)
          acc[p] += cm[j] * fmaxf(cx[j][p] + t[j][p], 0.f);

#pragma unroll
      for (int j = 0; j < 4; ++j) {
        ce[j] = ne[j];
        cs[j] = ns_[j];
        cm[j] = nm[j];
#pragma unroll
        for (int p = 0; p < FPL; ++p) cx[j][p] = nx[j][p];
      }
    }
  }
#pragma unroll
  for (int p = 0; p < FPL; ++p)
    hpre[(size_t)n * DIN + p * 64 + lane] =
        x[(size_t)n * DIN + p * 64 + lane] + acc[p];
}

// ---------------------------------------------------------------------------
// Fused per-layer MLP: out = relu(BN(relu(in@w1+b1) @ w2 + b2)).
// 32 nodes/block; each thread computes a 4-node x 4-col register tile. w2 is
// staged into the same LDS region as w1/hin after phase 1.
// ---------------------------------------------------------------------------
template <int K, int M>
__global__ __launch_bounds__((M / 4) * 8) void mlp_fused(
    const float* __restrict__ in, const float* __restrict__ w1,
    const float* __restrict__ b1, const float* __restrict__ w2,
    const float* __restrict__ b2, const float* __restrict__ bng,
    const float* __restrict__ bnb, const float* __restrict__ bnm,
    const float* __restrict__ bnv, float* __restrict__ out, int N) {
  constexpr int NPB = 32;
  constexpr int SK = K + 4;
  constexpr int SH = M + 4;
  constexpr int Q = M / 4;
  constexpr int TH = Q * 8;
  constexpr int R1 = K * M + NPB * SK;
  constexpr int SZA = (R1 > M * M) ? R1 : (M * M);
  __shared__ alignas(16) float smem[SZA + NPB * SH + 2 * M];
  float* w1l = smem;
  float* hin = smem + K * M;
  float* w2l = smem;
  float* h1 = smem + SZA;
  float* bnA = h1 + NPB * SH;
  float* bnB = bnA + M;

  const int tid = threadIdx.x;
  const int nb = blockIdx.x * NPB;

  for (int i = tid; i < K * M / 4; i += TH)
    ((float4*)w1l)[i] = ((const float4*)w1)[i];
  for (int f = tid; f < M; f += TH) {
    const float s = bng[f] * rsqrtf(bnv[f] + 1e-5f);
    bnA[f] = s;
    bnB[f] = bnb[f] - bnm[f] * s;
  }
  for (int i = tid; i < NPB * (K / 4); i += TH) {
    const int dn = i / (K / 4);
    const int kq = i % (K / 4);
    const int n = nb + dn;
    float4 v = make_float4(0.f, 0.f, 0.f, 0.f);
    if (n < N) v = ((const float4*)(in + (size_t)n * K))[kq];
    ((float4*)(hin + dn * SK))[kq] = v;
  }
  __syncthreads();

  const int q = tid % Q;
  const int ng = tid / Q;

  // phase 1: h1 = relu(in @ w1 + b1)
  {
    const float4 bias = ((const float4*)b1)[q];
    float4 a[4] = {bias, bias, bias, bias};
#pragma unroll 4
    for (int k = 0; k < K; ++k) {
      const float4 wv = ((const float4*)w1l)[k * Q + q];
#pragma unroll
      for (int r = 0; r < 4; ++r) {
        const float hv = hin[(ng * 4 + r) * SK + k];
        a[r].x = fmaf(hv, wv.x, a[r].x);
        a[r].y = fmaf(hv, wv.y, a[r].y);
        a[r].z = fmaf(hv, wv.z, a[r].z);
        a[r].w = fmaf(hv, wv.w, a[r].w);
      }
    }
    __syncthreads();  // all reads of w1l/hin done before w2l overwrite
#pragma unroll
    for (int r = 0; r < 4; ++r) {
      float4 v = a[r];
      v.x = fmaxf(v.x, 0.f);
      v.y = fmaxf(v.y, 0.f);
      v.z = fmaxf(v.z, 0.f);
      v.w = fmaxf(v.w, 0.f);
      ((float4*)(h1 + (ng * 4 + r) * SH))[q] = v;
    }
  }
  for (int i = tid; i < M * M / 4; i += TH)
    ((float4*)w2l)[i] = ((const float4*)w2)[i];
  __syncthreads();

  // phase 2: out = relu(BN(h1 @ w2 + b2))
  {
    const float4 bias = ((const float4*)b2)[q];
    float4 a[4] = {bias, bias, bias, bias};
#pragma unroll 4
    for (int k = 0; k < M; ++k) {
      const float4 wv = ((const float4*)w2l)[k * Q + q];
#pragma unroll
      for (int r = 0; r < 4; ++r) {
        const float hv = h1[(ng * 4 + r) * SH + k];
        a[r].x = fmaf(hv, wv.x, a[r].x);
        a[r].y = fmaf(hv, wv.y, a[r].y);
        a[r].z = fmaf(hv, wv.z, a[r].z);
        a[r].w = fmaf(hv, wv.w, a[r].w);
      }
    }
    const float4 A = ((const float4*)bnA)[q];
    const float4 B = ((const float4*)bnB)[q];
#pragma unroll
    for (int r = 0; r < 4; ++r) {
      const int n = nb + ng * 4 + r;
      if (n < N) {
        float4 v = a[r];
        v.x = fmaxf(fmaf(v.x, A.x, B.x), 0.f);
        v.y = fmaxf(fmaf(v.y, A.y, B.y), 0.f);
        v.z = fmaxf(fmaf(v.z, A.z, B.z), 0.f);
        v.w = fmaxf(fmaf(v.w, A.w, B.w), 0.f);
        ((float4*)(out + (size_t)n * M))[q] = v;
      }
    }
  }
}

// ---------------------------------------------------------------------------
// Global mean pool over sorted batch ids.
// ---------------------------------------------------------------------------
__global__ __launch_bounds__(128) void pool_kernel(const float* __restrict__ h,
                                                   const int* __restrict__ batch,
                                                   float* __restrict__ sums,
                                                   int* __restrict__ cnt, int N) {
  const int f = threadIdx.x;
  const int chunk = (N + gridDim.x - 1) / gridDim.x;
  const int n0 = blockIdx.x * chunk;
  const int n1 = min(n0 + chunk, N);
  int curg = -1;
  float acc = 0.f;
  int c = 0;
  for (int n = n0; n < n1; ++n) {
    const int g = batch[n];
    if (g != curg) {
      if (curg >= 0) {
        if (f < 96) unsafeAtomicAdd(&sums[curg * 96 + f], acc);
        if (f == 0) atomicAdd(&cnt[curg], c);
      }
      curg = g;
      acc = 0.f;
      c = 0;
    }
    if (f < 96) acc += h[(size_t)n * 96 + f];
    ++c;
  }
  if (curg >= 0) {
    if (f < 96) unsafeAtomicAdd(&sums[curg * 96 + f], acc);
    if (f == 0) atomicAdd(&cnt[curg], c);
  }
}

__global__ void finalize_kernel(const float* __restrict__ sums,
                                const int* __restrict__ cnt, float* __restrict__ out) {
  const int i = blockIdx.x * blockDim.x + threadIdx.x;
  if (i < N_GRAPHS * 96) {
    const int g = i / 96;
    const float c = (float)cnt[g];
    out[i] = sums[i] / fmaxf(c, 1.f);
  }
}

// ---------------------------------------------------------------------------
extern "C" void kernel_launch(void* const* d_in, const int* in_sizes, int n_in,
                              void* d_out, int out_size, void* d_ws, size_t ws_size,
                              hipStream_t stream) {
  const int N = N_NODES;
  const int E = N_EDGES;

  const float* x = (const float*)d_in[0];
  const float* ea = (const float*)d_in[1];
  const int* ei = (const int*)d_in[2];
  const int* batch = (const int*)d_in[3];
  auto L = [&](int l, int idx) { return (const float*)d_in[4 + 10 * l + idx]; };
  // per-layer: le_w(0) le_b(1) w1(2) b1(3) w2(4) b2(5) bng(6) bnb(7) bnm(8) bnv(9)

  // ---- workspace layout
  int* iws = (int*)d_ws;
  int* deg = iws;                       // N
  int* row_start = deg + N;             // N+1
  int* cursor = row_start + N + 1;      // N
  int2* epair = (int2*)(iws + 150004);  // E pairs
  float* fws = (float*)(iws + 150004 + 2 * E);  // 16B aligned
  float* hpre = fws;                    // N*128 max
  float* hA = hpre + (size_t)N * 128;   // N*96
  float* hB = hA + (size_t)N * 96;      // N*64
  float* sums = hB + (size_t)N * 64;    // G*96
  int* cnt = (int*)(sums + N_GRAPHS * 96);

  const int gE = (E + 255) / 256;
  const int gW = (N + 3) / 4;  // one wave per node
  const int gN32 = (N + 31) / 32;

  // ---- CSR build
  hipMemsetAsync(deg, 0, (size_t)N * 4, stream);
  hist_kernel<<<gE, 256, 0, stream>>>(ei, deg, E);
  scan_kernel<<<1, 1024, 0, stream>>>(deg, row_start, cursor, N);
  scatter_kernel<<<gE, 256, 0, stream>>>(ei, cursor, epair, E);

  // ---- Layer 0: din=128 -> 64
  gine_gather<128><<<gW, 256, 0, stream>>>(
      x, ea, row_start, epair, L(0, 0), L(0, 1), hpre, N);
  mlp_fused<128, 64><<<gN32, 128, 0, stream>>>(
      hpre, L(0, 2), L(0, 3), L(0, 4), L(0, 5), L(0, 6), L(0, 7), L(0, 8), L(0, 9), hA, N);

  // ---- Layer 1: din=64 -> 64
  gine_gather<64><<<gW, 256, 0, stream>>>(
      hA, ea, row_start, epair, L(1, 0), L(1, 1), hpre, N);
  mlp_fused<64, 64><<<gN32, 128, 0, stream>>>(
      hpre, L(1, 2), L(1, 3), L(1, 4), L(1, 5), L(1, 6), L(1, 7), L(1, 8), L(1, 9), hB, N);

  // ---- Layer 2: din=64 -> 96
  gine_gather<64><<<gW, 256, 0, stream>>>(
      hB, ea, row_start, epair, L(2, 0), L(2, 1), hpre, N);
  mlp_fused<64, 96><<<gN32, 192, 0, stream>>>(
      hpre, L(2, 2), L(2, 3), L(2, 4), L(2, 5), L(2, 6), L(2, 7), L(2, 8), L(2, 9), hA, N);

  // ---- Global mean pool
  hipMemsetAsync(sums, 0, (size_t)(N_GRAPHS * 96 + N_GRAPHS) * 4, stream);
  pool_kernel<<<512, 128, 0, stream>>>(hA, batch, sums, cnt, N);
  finalize_kernel<<<48, 128, 0, stream>>>(sums, cnt, (float*)d_out);
}